// Round 15
// baseline (361.425 us; speedup 1.0000x reference)
//
#include <hip/hip_runtime.h>
#include <math.h>

#define IDIM 2048
#define NE   64
#define TOPK 8
#define NB   16384
#define BM   32            // rows per (single-wave) block
#define BKT  32            // k per tile
#define NT   (IDIM / BKT)  // 64 tiles
#define TAU  5e-4f
#define BUFB 20480         // per-buffer bytes: A 4KB @0, WH 8KB @4096, WL 8KB @12288

// ws float layout: [0..63] f counts, [64..127] p sums, [128] z sum,
//                  [129] (int) flag count, [130..130+NB) (int) flagged row list
// byte WSPLIT_BYTE..: pre-split W images: 64 tiles x 16KB (WH 8KB + WL 8KB), swizzle baked
#define WS_CNT 129
#define WS_LIST 130
#define WSPLIT_BYTE 66560
#define WSPLIT_REQ  (WSPLIT_BYTE + NT * 16384)

typedef __attribute__((ext_vector_type(8))) short bf16x8_t;
typedef __attribute__((ext_vector_type(4))) float f32x4_t;

#define MFMA __builtin_amdgcn_mfma_f32_16x16x32_bf16

__device__ __forceinline__ float softplusf(float v) {
    return (v > 0.f) ? (v + log1pf(expf(-v))) : log1pf(expf(v));
}
__device__ __forceinline__ double softplus_d(double v) {
    return (v > 0.0) ? (v + log1p(exp(-v))) : log1p(exp(v));
}

__device__ __forceinline__ short f2bf(float f) {
    unsigned u = __float_as_uint(f);
    unsigned r = (u + 0x7FFFu + ((u >> 16) & 1u)) >> 16;
    return (short)r;
}
__device__ __forceinline__ float bf2f(short s) {
    return __uint_as_float(((unsigned)(unsigned short)s) << 16);
}

__device__ __forceinline__ void split8(const float4 v0, const float4 v1,
                                       bf16x8_t& H, bf16x8_t& L) {
    float fv[8] = {v0.x, v0.y, v0.z, v0.w, v1.x, v1.y, v1.z, v1.w};
    #pragma unroll
    for (int q = 0; q < 8; ++q) {
        short hb = f2bf(fv[q]);
        H[q] = hb;
        L[q] = f2bf(fv[q] - bf2f(hb));
    }
}

// HW packed split: 8 f32 -> hi/lo bf16 (v_cvt_pk_bf16_f32, dst.lo = src0)
__device__ __forceinline__ void split8_pk(const float4 v0, const float4 v1,
                                          bf16x8_t& H, bf16x8_t& L) {
    float fv[8] = {v0.x, v0.y, v0.z, v0.w, v1.x, v1.y, v1.z, v1.w};
    int hp[4], lp[4];
    #pragma unroll
    for (int p = 0; p < 4; ++p) {
        float a = fv[2 * p], b = fv[2 * p + 1];
        int h;
        asm("v_cvt_pk_bf16_f32 %0, %1, %2" : "=v"(h) : "v"(a), "v"(b));
        float ra = a - __uint_as_float(((unsigned)h) << 16);
        float rb = b - __uint_as_float(((unsigned)h) & 0xFFFF0000u);
        int lo_;
        asm("v_cvt_pk_bf16_f32 %0, %1, %2" : "=v"(lo_) : "v"(ra), "v"(rb));
        hp[p] = h; lp[p] = lo_;
    }
    int4 Hi = {hp[0], hp[1], hp[2], hp[3]};
    int4 Lo = {lp[0], lp[1], lp[2], lp[3]};
    __builtin_memcpy(&H, &Hi, 16);
    __builtin_memcpy(&L, &Lo, 16);
}

__global__ void init_ws_kernel(float* ws) {
    int t = threadIdx.x;
    if (t < WS_LIST) ws[t] = 0.0f;
}

// ---------------- pass 0: init ws + pre-split W into per-BK32 swizzled images ----------------
// image tile t (16KB): WH byte (c*64 + s*16) holds k-group (s ^ ((c>>1)&3)); WL at +8192
__global__ __launch_bounds__(256) void prep_kernel(
    const float* __restrict__ Wg, const float* __restrict__ Wn,
    char* __restrict__ wsW, float* __restrict__ ws)
{
    if (blockIdx.x == 128) {
        if (threadIdx.x < WS_LIST) ws[threadIdx.x] = 0.0f;
        return;
    }
    int g = blockIdx.x * 256 + threadIdx.x;   // 0..32767
    int t = g >> 9, i = g & 511;
    int c = i >> 2, s = i & 3;
    int kg = s ^ ((c >> 1) & 3);
    const float* src = (c < 64 ? Wg + (size_t)c * IDIM
                               : Wn + (size_t)(c - 64) * IDIM) + t * BKT + kg * 8;
    float4 v0 = *(const float4*)src;
    float4 v1 = *(const float4*)(src + 4);
    bf16x8_t H, L;
    split8(v0, v1, H, L);
    char* dst = wsW + (size_t)t * 16384 + c * 64 + s * 16;
    *(bf16x8_t*)dst          = H;
    *(bf16x8_t*)(dst + 8192) = L;
}

// ---------------- pass 1: single-wave, zero-barrier, counted-vmcnt MFMA GEMM + gating ----------------
// LDS 61440B: 3 buffers x 20480 (A fp32 4KB @0, WH @4096, WL @12288); sL aliased post-loop
template<bool PRE>
__global__ __launch_bounds__(64, 1) void gate_main_kernel(
    const float* __restrict__ x, const float* __restrict__ noise,
    const float* __restrict__ Wg, const float* __restrict__ bg,
    const float* __restrict__ Wn, const char* __restrict__ wsW,
    float* __restrict__ out_w, float* __restrict__ out_i,
    float* __restrict__ ws, int listCap)
{
    __shared__ char smem[61440] __attribute__((aligned(16)));

    const int l  = threadIdx.x;
    const int lr = l & 15;
    const int kg = l >> 4;               // 0..3
    const int row0 = blockIdx.x * BM;

    // A DMA sources: op j writes linear slot i=j*64+l -> (row=i>>3, slot=i&7),
    // content k-group kslot = slot ^ (row&7)
    const float* asrc[4];
    #pragma unroll
    for (int j = 0; j < 4; ++j) {
        int i = j * 64 + l;
        int row = i >> 3, slot = i & 7;
        int ks = slot ^ (row & 7);
        asrc[j] = x + (size_t)(row0 + row) * IDIM + ks * 4;
    }

    f32x4_t acc[2][8];
    #pragma unroll
    for (int rt = 0; rt < 2; ++rt)
        #pragma unroll
        for (int ct = 0; ct < 8; ++ct) {
            f32x4_t z = {0.f, 0.f, 0.f, 0.f};
            acc[rt][ct] = z;
        }

#define DMAT(tt, bufi) do {                                                         \
    char* bp_ = smem + (bufi) * BUFB;                                               \
    _Pragma("unroll")                                                               \
    for (int j_ = 0; j_ < 4; ++j_)                                                  \
        __builtin_amdgcn_global_load_lds(                                           \
            (const __attribute__((address_space(1))) void*)(asrc[j_] + (tt) * BKT), \
            (__attribute__((address_space(3))) void*)(bp_ + j_ * 1024), 16, 0, 0);  \
    if constexpr (PRE) {                                                            \
        const char* img_ = wsW + (size_t)(tt) * 16384 + l * 16;                     \
        _Pragma("unroll")                                                           \
        for (int j_ = 0; j_ < 16; ++j_)                                             \
            __builtin_amdgcn_global_load_lds(                                       \
                (const __attribute__((address_space(1))) void*)(img_ + j_ * 1024),  \
                (__attribute__((address_space(3))) void*)(bp_ + 4096 + j_ * 1024),  \
                16, 0, 0);                                                          \
    }                                                                               \
} while (0)

#define FSTW(tt, bufi) do {                                                   \
    char* bp_ = smem + (bufi) * BUFB;                                         \
    for (int idx_ = l; idx_ < 512; idx_ += 64) {                              \
        int c_ = idx_ >> 2, s_ = idx_ & 3;                                    \
        int kg_ = s_ ^ ((c_ >> 1) & 3);                                       \
        const float* pw_ = (c_ < 64 ? Wg + (size_t)c_ * IDIM                  \
                                    : Wn + (size_t)(c_ - 64) * IDIM)          \
                           + (tt) * BKT + kg_ * 8;                            \
        float4 v0_ = *(const float4*)pw_;                                     \
        float4 v1_ = *(const float4*)(pw_ + 4);                               \
        bf16x8_t H_, L_;                                                      \
        split8(v0_, v1_, H_, L_);                                             \
        *(bf16x8_t*)(bp_ + 4096 + c_ * 64 + s_ * 16)  = H_;                   \
        *(bf16x8_t*)(bp_ + 12288 + c_ * 64 + s_ * 16) = L_;                   \
    }                                                                         \
} while (0)

    // ---- prologue: two tiles in flight ----
    DMAT(0, 0);
    DMAT(1, 1);
    if constexpr (!PRE) { FSTW(0, 0); FSTW(1, 1); }

    for (int t = 0; t < NT; ++t) {
        const int cur = t % 3;
        // counted wait: tile t landed, tile t+1 stays in flight (20 ops)
        if constexpr (PRE) {
            if (t < NT - 1) { asm volatile("s_waitcnt vmcnt(20) lgkmcnt(0)" ::: "memory"); }
            else            { asm volatile("s_waitcnt vmcnt(0) lgkmcnt(0)" ::: "memory"); }
        } else {
            asm volatile("s_waitcnt vmcnt(0) lgkmcnt(0)" ::: "memory");
        }
        __builtin_amdgcn_sched_barrier(0);

        if (t + 2 < NT) {
            DMAT(t + 2, (t + 2) % 3);
            if constexpr (!PRE) FSTW(t + 2, (t + 2) % 3);
        }

        // ---- compute tile t ----
        char* bp = smem + cur * BUFB;
        bf16x8_t ah[2], al_[2];
        #pragma unroll
        for (int rt = 0; rt < 2; ++rt) {
            const int row = rt * 16 + lr;
            const int k0 = (kg * 2)     ^ (row & 7);
            const int k1 = (kg * 2 + 1) ^ (row & 7);
            float4 a0 = *(const float4*)(bp + row * 128 + k0 * 16);
            float4 a1 = *(const float4*)(bp + row * 128 + k1 * 16);
            split8_pk(a0, a1, ah[rt], al_[rt]);
        }
        #pragma unroll
        for (int ct = 0; ct < 8; ++ct) {
            const int c = ct * 16 + lr;
            const int so = (kg ^ ((c >> 1) & 3)) * 16;
            bf16x8_t bh = *(const bf16x8_t*)(bp + 4096 + c * 64 + so);
            bf16x8_t bl = *(const bf16x8_t*)(bp + 12288 + c * 64 + so);
            #pragma unroll
            for (int rt = 0; rt < 2; ++rt) {
                acc[rt][ct] = MFMA(ah[rt],  bh, acc[rt][ct], 0, 0, 0);
                acc[rt][ct] = MFMA(ah[rt],  bl, acc[rt][ct], 0, 0, 0);
                acc[rt][ct] = MFMA(al_[rt], bh, acc[rt][ct], 0, 0, 0);
            }
        }
    }
    __syncthreads();   // single wave: trivial; orders LDS for aliasing

    // ---- epilogue: acc -> sL[32][132]  (C/D: col=lane&15, row=(lane>>4)*4+reg) ----
    float* sL = (float*)smem;
    #pragma unroll
    for (int rt = 0; rt < 2; ++rt)
        #pragma unroll
        for (int ct = 0; ct < 8; ++ct)
            #pragma unroll
            for (int r = 0; r < 4; ++r)
                sL[(rt * 16 + kg * 4 + r) * 132 + ct * 16 + lr] = acc[rt][ct][r];
    __syncthreads();

    // ---- gating: 32 rows serial, lane = expert ----
    const float bgl = bg[l];
    float pacc = 0.f, zacc = 0.f;
    int   fcnt = 0;

    #pragma unroll 1
    for (int rr = 0; rr < 32; ++rr) {
        const int grow = row0 + rr;
        float lg   = sL[rr * 132 + l] + bgl;
        float npre = sL[rr * 132 + 64 + l];
        float vcur = fmaf(noise[(size_t)grow * NE + l], softplusf(npre), lg);

        float tkv[9]; int tki[9];
        #pragma unroll
        for (int k = 0; k < 9; ++k) {
            float mv = vcur; int mi = l;
            #pragma unroll
            for (int o = 32; o > 0; o >>= 1) {
                float ov = __shfl_xor(mv, o);
                int   oi = __shfl_xor(mi, o);
                if (ov > mv || (ov == mv && oi < mi)) { mv = ov; mi = oi; }
            }
            tkv[k] = mv; tki[k] = mi;
            if (l == mi) vcur = -1e30f;
        }

        float m0 = tkv[0], s = 0.f, wk[TOPK];
        #pragma unroll
        for (int k = 0; k < TOPK; ++k) { wk[k] = expf(tkv[k] - m0); s += wk[k]; }
        float inv = 1.f / s;
        float myw = 0.f; int myi = 0;
        #pragma unroll
        for (int k = 0; k < TOPK; ++k)
            if (l == k) { myw = wk[k] * inv; myi = tki[k]; }
        if (l < TOPK) {
            out_w[(size_t)grow * TOPK + l] = myw;
            out_i[(size_t)grow * TOPK + l] = (float)myi;
        }

        fcnt += (tki[0] == l) ? 1 : 0;

        if (l == 0) {
            float ming = 1e30f;
            #pragma unroll
            for (int k = 0; k < 8; ++k) ming = fminf(ming, tkv[k] - tkv[k + 1]);
            if (ming < TAU) {
                int slot = atomicAdd((int*)&ws[WS_CNT], 1);
                if (slot < listCap) ((int*)ws)[WS_LIST + slot] = grow;
            }
        }

        float rm = lg;
        #pragma unroll
        for (int o = 32; o > 0; o >>= 1) rm = fmaxf(rm, __shfl_xor(rm, o));
        float pe = expf(lg - rm);
        float ssum = pe;
        #pragma unroll
        for (int o = 32; o > 0; o >>= 1) ssum += __shfl_xor(ssum, o);
        pacc += pe / ssum;
        float lse = rm + logf(ssum);
        zacc += lse * lse;               // wave-uniform
    }

    atomicAdd(&ws[l],      (float)fcnt);
    atomicAdd(&ws[NE + l], pacc);
    if (l == 0) atomicAdd(&ws[2 * NE], zacc);
}

// ---------------- pass 2: finalize scalars (block 0) + fp64 recheck, 1 row/block ----------------
__global__ __launch_bounds__(512) void recheck_finalize_kernel(
    const float* __restrict__ x, const float* __restrict__ noise,
    const float* __restrict__ Wg, const float* __restrict__ bg,
    const float* __restrict__ Wn,
    float* __restrict__ out_w, float* __restrict__ out_i, float* __restrict__ out_s,
    const float* __restrict__ ws, int listCap)
{
    __shared__ double sRed[512];
    const int t = threadIdx.x;

    if (blockIdx.x == 0 && t < 64) {
        float v = (ws[t] / (float)NB) * (ws[NE + t] / (float)NB);
        #pragma unroll
        for (int o = 32; o > 0; o >>= 1) v += __shfl_down(v, o);
        if (t == 0) {
            out_s[0] = (float)NE * v;
            out_s[1] = ws[2 * NE] / (float)NB;
        }
    }

    const int* wsi = (const int*)ws;
    int cnt = wsi[WS_CNT];
    if (cnt > listCap) cnt = listCap;
    if (cnt <= 0) return;

    const int slot = t & 127;
    const int q4   = t >> 7;
    const float* wrb = ((slot < 64) ? (Wg + (size_t)slot * IDIM)
                                    : (Wn + (size_t)(slot - 64) * IDIM)) + q4 * 512;

    for (int bi = blockIdx.x; bi < cnt; bi += gridDim.x) {
        const int row = wsi[WS_LIST + bi];
        const float* xr = x + (size_t)row * IDIM + q4 * 512;

        double a = 0.0;
        #pragma unroll 4
        for (int k = 0; k < 512; k += 4) {
            float4 wv = *(const float4*)(wrb + k);
            float4 xv = *(const float4*)(xr + k);
            a = fma((double)xv.x, (double)wv.x, a);
            a = fma((double)xv.y, (double)wv.y, a);
            a = fma((double)xv.z, (double)wv.z, a);
            a = fma((double)xv.w, (double)wv.w, a);
        }
        sRed[t] = a;
        __syncthreads();
        if (t < 128)
            sRed[t] = sRed[t] + sRed[t + 128] + sRed[t + 256] + sRed[t + 384];
        __syncthreads();

        if (t < 64) {
            const int lane = t;
            double g = sRed[lane];
            double n = sRed[64 + lane];
            double lgd = g + (double)bg[lane];
            double nz = (double)noise[(size_t)row * NE + lane];
            double vcur = fma(nz, softplus_d(n), lgd);

            double tkv[TOPK]; int tki[TOPK];
            #pragma unroll
            for (int k = 0; k < TOPK; ++k) {
                double mv = vcur; int mi = lane;
                #pragma unroll
                for (int o = 32; o > 0; o >>= 1) {
                    double ov = __shfl_xor(mv, o);
                    int    oi = __shfl_xor(mi, o);
                    if (ov > mv || (ov == mv && oi < mi)) { mv = ov; mi = oi; }
                }
                tkv[k] = mv; tki[k] = mi;
                if (lane == mi) vcur = -1e300;
            }
            double m0 = tkv[0], s = 0.0, wk[TOPK];
            #pragma unroll
            for (int k = 0; k < TOPK; ++k) { wk[k] = exp(tkv[k] - m0); s += wk[k]; }
            double inv = 1.0 / s;
            float myw = 0.f; int myi = 0;
            #pragma unroll
            for (int k = 0; k < TOPK; ++k)
                if (lane == k) { myw = (float)(wk[k] * inv); myi = tki[k]; }
            if (lane < TOPK) {
                out_w[(size_t)row * TOPK + lane] = myw;
                out_i[(size_t)row * TOPK + lane] = (float)myi;
            }
        }
        __syncthreads();
    }
}

extern "C" void kernel_launch(void* const* d_in, const int* in_sizes, int n_in,
                              void* d_out, int out_size, void* d_ws, size_t ws_size,
                              hipStream_t stream) {
    const float* x     = (const float*)d_in[0];
    const float* noise = (const float*)d_in[1];
    const float* Wg    = (const float*)d_in[2];
    const float* bg    = (const float*)d_in[3];
    const float* Wn    = (const float*)d_in[4];
    float* out = (float*)d_out;
    float* ws  = (float*)d_ws;
    char*  wsW = (char*)d_ws + WSPLIT_BYTE;

    long cap = (long)(ws_size / 4) - WS_LIST;
    int listCap = (int)(cap < 0 ? 0 : (cap > NB ? NB : cap));
    const bool pre = ws_size >= (size_t)WSPLIT_REQ;

    if (pre) {
        hipLaunchKernelGGL(prep_kernel, dim3(129), dim3(256), 0, stream, Wg, Wn, wsW, ws);
        hipLaunchKernelGGL(gate_main_kernel<true>, dim3(NB / BM), dim3(64), 0, stream,
                           x, noise, Wg, bg, Wn, wsW,
                           out, out + (size_t)NB * TOPK, ws, listCap);
    } else {
        hipLaunchKernelGGL(init_ws_kernel, dim3(1), dim3(256), 0, stream, ws);
        hipLaunchKernelGGL(gate_main_kernel<false>, dim3(NB / BM), dim3(64), 0, stream,
                           x, noise, Wg, bg, Wn, wsW,
                           out, out + (size_t)NB * TOPK, ws, listCap);
    }
    hipLaunchKernelGGL(recheck_finalize_kernel, dim3(1024), dim3(512), 0, stream,
                       x, noise, Wg, bg, Wn,
                       out, out + (size_t)NB * TOPK, out + 2 * (size_t)NB * TOPK,
                       ws, listCap);
}

// Round 16
// 142.227 us; speedup vs baseline: 2.5412x; 2.5412x over previous
//
#include <hip/hip_runtime.h>
#include <math.h>

#define IDIM 2048
#define NE   64
#define TOPK 8
#define NB   16384
#define BM   32            // rows per block
#define BK   64            // k per chunk
#define NCH  (IDIM / BK)   // 32 chunks
#define TAU  2.5e-4f

// ws float layout: [0..63] f counts, [64..127] p sums, [128] z sum,
//                  [129] (int) flag count, [130..130+NB) (int) flagged row list
// byte WSPLIT_BYTE..: pre-split W tiles (32 tiles x (16KB hi + 16KB lo))
#define WS_CNT 129
#define WS_LIST 130
#define WSPLIT_BYTE 66560
#define WSPLIT_REQ  (WSPLIT_BYTE + NCH * 32768)

typedef __attribute__((ext_vector_type(8))) short bf16x8_t;  // 8 bf16 = 4 VGPRs
typedef __attribute__((ext_vector_type(4))) float f32x4_t;   // MFMA acc

__device__ __forceinline__ float softplusf(float v) {
    return (v > 0.f) ? (v + log1pf(expf(-v))) : log1pf(expf(v));
}
__device__ __forceinline__ double softplus_d(double v) {
    return (v > 0.0) ? (v + log1p(exp(-v))) : log1p(exp(v));
}

// deterministic RNE fp32 -> bf16 bits
__device__ __forceinline__ short f2bf(float f) {
    unsigned u = __float_as_uint(f);
    unsigned r = (u + 0x7FFFu + ((u >> 16) & 1u)) >> 16;
    return (short)r;
}
__device__ __forceinline__ float bf2f(short s) {
    return __uint_as_float(((unsigned)(unsigned short)s) << 16);
}

__global__ void init_ws_kernel(float* ws) {
    int t = threadIdx.x;
    if (t < WS_LIST) ws[t] = 0.0f;
}

__device__ __forceinline__ void split8(const float4 v0, const float4 v1,
                                       bf16x8_t& H, bf16x8_t& L) {
    float fv[8] = {v0.x, v0.y, v0.z, v0.w, v1.x, v1.y, v1.z, v1.w};
    #pragma unroll
    for (int q = 0; q < 8; ++q) {
        short hb = f2bf(fv[q]);
        short lb = f2bf(fv[q] - bf2f(hb));
        H[q] = hb; L[q] = lb;
    }
}

__device__ __forceinline__ void cvt_slot(const float4 v0, const float4 v1,
                                         char* hiP, char* loP, int off) {
    bf16x8_t H, L;
    split8(v0, v1, H, L);
    *(bf16x8_t*)(hiP + off) = H;
    *(bf16x8_t*)(loP + off) = L;
}

// ---------------- pass 0: init ws + pre-split W into swizzled LDS tile images ----------------
__global__ __launch_bounds__(256) void prep_kernel(
    const float* __restrict__ Wg, const float* __restrict__ Wn,
    char* __restrict__ wsW, float* __restrict__ ws)
{
    if (blockIdx.x == 128) {             // merged init
        if (threadIdx.x < WS_LIST) ws[threadIdx.x] = 0.0f;
        return;
    }
    int g = blockIdx.x * 256 + threadIdx.x;   // 0..32767
    int t = g >> 10, i = g & 1023;
    int row = i >> 3, wslot = i & 7;
    int kslot = wslot ^ (row & 7);
    const float* src = (row < 64 ? Wg + (size_t)row * IDIM
                                 : Wn + (size_t)(row - 64) * IDIM) + t * BK + kslot * 8;
    float4 v0 = *(const float4*)src;
    float4 v1 = *(const float4*)(src + 4);
    bf16x8_t H, L;
    split8(v0, v1, H, L);
    char* dst = wsW + (size_t)t * 32768;
    *(bf16x8_t*)(dst + i * 16)         = H;
    *(bf16x8_t*)(dst + 16384 + i * 16) = L;
}

// ---------------- pass 1: split-bf16 MFMA GEMM + gating + flag near-ties ----------------
// (byte-for-byte the R8-measured 112 µs structure)
// LDS bytes: AH@0 (4096) AL@4096 (4096) BH@8192 (16384) BL@24576 (16384)
//   epilogue alias: sL f32[32][132] @0 ; sP@40960 sF@41216 sZ@41472
template<bool PRE>
__global__ __launch_bounds__(512, 4) void gate_main_kernel(
    const float* __restrict__ x, const float* __restrict__ noise,
    const float* __restrict__ Wg, const float* __restrict__ bg,
    const float* __restrict__ Wn, const char* __restrict__ wsW,
    float* __restrict__ out_w, float* __restrict__ out_i,
    float* __restrict__ ws, int listCap)
{
    __shared__ char smem[41488] __attribute__((aligned(16)));
    char* AH = smem;
    char* AL = smem + 4096;
    char* BH = smem + 8192;
    char* BL = smem + 24576;
    float* sP = (float*)(smem + 40960);
    float* sF = (float*)(smem + 41216);
    float* sZ = (float*)(smem + 41472);
    float* sL = (float*)smem;            // [32][132] epilogue alias

    const int u   = threadIdx.x;
    const int w   = u >> 6;              // wave 0..7, owns cols [w*16, w*16+16)
    const int l   = u & 63;
    const int lr  = l & 15;
    const int lg4 = l >> 4;
    const int s7  = lr & 7;
    const int row0 = blockIdx.x * BM;

    if (u < NE) { sP[u] = 0.f; sF[u] = 0.f; }
    if (u == 0) sZ[0] = 0.f;

    // A staging: threads 0..255, one 8-float slot each
    const int ar  = (u >> 3) & 31;
    const int ac  = u & 7;
    const int aoff = ar * 128 + (((ac ^ (ar & 7)) & 7) << 4);
    const float* pa = x + (size_t)(row0 + ar) * IDIM + ac * 8;

    // fallback W staging: thread u handles Wg[br] and Wn[br] slot ac
    const int br  = u >> 3;              // 0..63
    const float* pg = Wg + (size_t)br * IDIM + ac * 8;
    const float* pn = Wn + (size_t)br * IDIM + ac * 8;
    const int woff = br * 128 + ((ac ^ (br & 7)) << 4);

    f32x4_t acc[2];
    #pragma unroll
    for (int mt = 0; mt < 2; ++mt) {
        f32x4_t z = {0.f, 0.f, 0.f, 0.f};
        acc[mt] = z;
    }

    float4 ra0, ra1;                 // x in-flight
    int4 w0, w1, w2, w3;             // PRE: W in-flight (pre-split)
    float4 g0, g1, n0, n1;           // !PRE: W floats in-flight

#define LOADT(tt) { const int k0 = (tt) * BK;                                   \
    if (u < 256) { ra0 = *(const float4*)(pa + k0);                             \
                   ra1 = *(const float4*)(pa + k0 + 4); }                       \
    if constexpr (PRE) {                                                        \
        const char* s_ = wsW + (size_t)(tt) * 32768 + u * 16;                   \
        w0 = *(const int4*)(s_);          w1 = *(const int4*)(s_ + 8192);       \
        w2 = *(const int4*)(s_ + 16384);  w3 = *(const int4*)(s_ + 24576);      \
    } else {                                                                    \
        g0 = *(const float4*)(pg + k0);   g1 = *(const float4*)(pg + k0 + 4);   \
        n0 = *(const float4*)(pn + k0);   n1 = *(const float4*)(pn + k0 + 4);   \
    } }

    LOADT(0);

    for (int t = 0; t < NCH; ++t) {
        __syncthreads();                 // previous tile's LDS reads complete
        if (u < 256) cvt_slot(ra0, ra1, AH, AL, aoff);
        if constexpr (PRE) {
            *(int4*)(BH + u * 16)        = w0;
            *(int4*)(BH + 8192 + u * 16) = w1;
            *(int4*)(BL + u * 16)        = w2;
            *(int4*)(BL + 8192 + u * 16) = w3;
        } else {
            cvt_slot(g0, g1, BH, BL, woff);
            cvt_slot(n0, n1, BH, BL, woff + 8192);
        }
        if (t + 1 < NCH) LOADT(t + 1);   // next-tile loads land during compute
        __syncthreads();                 // staging visible

        #pragma unroll
        for (int ks = 0; ks < 2; ++ks) {
            const int so = (((ks * 4 + lg4) ^ s7) << 4);
            bf16x8_t ah[2], al_[2], bh, bl;
            #pragma unroll
            for (int mt = 0; mt < 2; ++mt) {
                const int o = (mt * 16 + lr) * 128 + so;
                ah[mt]  = *(const bf16x8_t*)(AH + o);
                al_[mt] = *(const bf16x8_t*)(AL + o);
            }
            {
                const int o = (w * 16 + lr) * 128 + so;
                bh = *(const bf16x8_t*)(BH + o);
                bl = *(const bf16x8_t*)(BL + o);
            }
            #pragma unroll
            for (int mt = 0; mt < 2; ++mt) {
                acc[mt] = __builtin_amdgcn_mfma_f32_16x16x32_bf16(ah[mt],  bh, acc[mt], 0, 0, 0);
                acc[mt] = __builtin_amdgcn_mfma_f32_16x16x32_bf16(ah[mt],  bl, acc[mt], 0, 0, 0);
                acc[mt] = __builtin_amdgcn_mfma_f32_16x16x32_bf16(al_[mt], bh, acc[mt], 0, 0, 0);
            }
        }
    }
    __syncthreads();   // staging dead; safe to alias

    // ---- epilogue: acc -> sL[32][132]  (C/D: col=lane&15, row=(lane>>4)*4+reg) ----
    #pragma unroll
    for (int mt = 0; mt < 2; ++mt)
        #pragma unroll
        for (int r = 0; r < 4; ++r)
            sL[(mt * 16 + lg4 * 4 + r) * 132 + (w * 16 + lr)] = acc[mt][r];
    __syncthreads();

    // ---- gating: 8 waves x 4 rows, lane = expert ----
    float pacc = 0.f, zacc = 0.f;
    #pragma unroll 1
    for (int rr = 0; rr < 4; ++rr) {
        const int r = w * 4 + rr;
        const int grow = row0 + r;
        float lg   = sL[r * 132 + l] + bg[l];
        float npre = sL[r * 132 + 64 + l];
        float vcur = fmaf(noise[(size_t)grow * NE + l], softplusf(npre), lg);

        float tkv[9]; int tki[9];
        #pragma unroll
        for (int k = 0; k < 9; ++k) {
            float mv = vcur; int mi = l;
            #pragma unroll
            for (int o = 32; o > 0; o >>= 1) {
                float ov = __shfl_xor(mv, o);
                int   oi = __shfl_xor(mi, o);
                if (ov > mv || (ov == mv && oi < mi)) { mv = ov; mi = oi; }
            }
            tkv[k] = mv; tki[k] = mi;
            if (l == mi) vcur = -1e30f;
        }

        float m0 = tkv[0], s = 0.f, wk[TOPK];
        #pragma unroll
        for (int k = 0; k < TOPK; ++k) { wk[k] = expf(tkv[k] - m0); s += wk[k]; }
        float inv = 1.f / s;
        float myw = 0.f; int myi = 0;
        #pragma unroll
        for (int k = 0; k < TOPK; ++k)
            if (l == k) { myw = wk[k] * inv; myi = tki[k]; }
        if (l < TOPK) {
            out_w[(size_t)grow * TOPK + l] = myw;
            out_i[(size_t)grow * TOPK + l] = (float)myi;
        }

        if (l == 0) {
            atomicAdd(&sF[tki[0]], 1.f);
            float ming = 1e30f;
            #pragma unroll
            for (int k = 0; k < 8; ++k) ming = fminf(ming, tkv[k] - tkv[k + 1]);
            if (ming < TAU) {
                int slot = atomicAdd((int*)&ws[WS_CNT], 1);
                if (slot < listCap) ((int*)ws)[WS_LIST + slot] = grow;
            }
        }

        float rm = lg;
        #pragma unroll
        for (int o = 32; o > 0; o >>= 1) rm = fmaxf(rm, __shfl_xor(rm, o));
        float pe = expf(lg - rm);
        float ssum = pe;
        #pragma unroll
        for (int o = 32; o > 0; o >>= 1) ssum += __shfl_xor(ssum, o);
        pacc += pe / ssum;
        if (l == 0) { float lse = rm + logf(ssum); zacc += lse * lse; }
    }

    atomicAdd(&sP[l], pacc);
    if (l == 0) atomicAdd(sZ, zacc);
    __syncthreads();
    if (u < NE) {
        atomicAdd(&ws[u],      sF[u]);
        atomicAdd(&ws[NE + u], sP[u]);
    }
    if (u == 0) atomicAdd(&ws[2 * NE], sZ[0]);
}

// ---------------- pass 2: finalize scalars (block 0) + fp64 recheck, 2 rows/block ----------------
// 512 threads = 128 dot-slots (0..63 Wg expert, 64..127 Wn expert) x 4 K-quarters.
// W read once per row PAIR (2x amortization); 2 independent fp64 chains per thread.
__global__ __launch_bounds__(512) void recheck_finalize_kernel(
    const float* __restrict__ x, const float* __restrict__ noise,
    const float* __restrict__ Wg, const float* __restrict__ bg,
    const float* __restrict__ Wn,
    float* __restrict__ out_w, float* __restrict__ out_i, float* __restrict__ out_s,
    const float* __restrict__ ws, int listCap)
{
    __shared__ double sRed[1024];        // [512 threads][2 rows]
    const int t = threadIdx.x;

    if (blockIdx.x == 0 && t < 64) {     // finalize scalars (wave 0, no barriers)
        float v = (ws[t] / (float)NB) * (ws[NE + t] / (float)NB);
        #pragma unroll
        for (int o = 32; o > 0; o >>= 1) v += __shfl_down(v, o);
        if (t == 0) {
            out_s[0] = (float)NE * v;
            out_s[1] = ws[2 * NE] / (float)NB;
        }
    }

    const int* wsi = (const int*)ws;
    int cnt = wsi[WS_CNT];
    if (cnt > listCap) cnt = listCap;
    if (cnt <= 0) return;

    const int slot = t & 127;            // 0..63: Wg expert; 64..127: Wn expert-64
    const int q4   = t >> 7;             // K quarter: [q4*512, +512)
    const float* wrb = ((slot < 64) ? (Wg + (size_t)slot * IDIM)
                                    : (Wn + (size_t)(slot - 64) * IDIM)) + q4 * 512;

    const int npair = (cnt + 1) >> 1;
    for (int bi = blockIdx.x; bi < npair; bi += gridDim.x) {
        const int i1 = 2 * bi + 1;
        const int r0 = wsi[WS_LIST + 2 * bi];
        const int r1 = wsi[WS_LIST + (i1 < cnt ? i1 : cnt - 1)];
        const float* x0 = x + (size_t)r0 * IDIM + q4 * 512;
        const float* x1 = x + (size_t)r1 * IDIM + q4 * 512;

        double a0 = 0.0, a1 = 0.0;
        #pragma unroll 4
        for (int k = 0; k < 512; k += 4) {
            float4 wv  = *(const float4*)(wrb + k);
            float4 xv0 = *(const float4*)(x0 + k);
            float4 xv1 = *(const float4*)(x1 + k);
            a0 = fma((double)xv0.x, (double)wv.x, a0);
            a1 = fma((double)xv1.x, (double)wv.x, a1);
            a0 = fma((double)xv0.y, (double)wv.y, a0);
            a1 = fma((double)xv1.y, (double)wv.y, a1);
            a0 = fma((double)xv0.z, (double)wv.z, a0);
            a1 = fma((double)xv1.z, (double)wv.z, a1);
            a0 = fma((double)xv0.w, (double)wv.w, a0);
            a1 = fma((double)xv1.w, (double)wv.w, a1);
        }
        sRed[t * 2]     = a0;
        sRed[t * 2 + 1] = a1;
        __syncthreads();
        if (t < 128) {
            #pragma unroll
            for (int i = 0; i < 2; ++i)
                sRed[t * 2 + i] = sRed[t * 2 + i] + sRed[(t + 128) * 2 + i]
                                + sRed[(t + 256) * 2 + i] + sRed[(t + 384) * 2 + i];
        }
        __syncthreads();

        if (t < 64) {
            const int lane = t;
            const double bgl = (double)bg[lane];
            #pragma unroll 1
            for (int i = 0; i < 2; ++i) {
                const int row = i ? r1 : r0;
                double g = sRed[lane * 2 + i];
                double n = sRed[(64 + lane) * 2 + i];
                double lgd = g + bgl;
                double nz = (double)noise[(size_t)row * NE + lane];
                double vcur = fma(nz, softplus_d(n), lgd);

                double tkv[TOPK]; int tki[TOPK];
                #pragma unroll
                for (int k = 0; k < TOPK; ++k) {
                    double mv = vcur; int mi = lane;
                    #pragma unroll
                    for (int o = 32; o > 0; o >>= 1) {
                        double ov = __shfl_xor(mv, o);
                        int    oi = __shfl_xor(mi, o);
                        if (ov > mv || (ov == mv && oi < mi)) { mv = ov; mi = oi; }
                    }
                    tkv[k] = mv; tki[k] = mi;
                    if (lane == mi) vcur = -1e300;
                }
                double m0 = tkv[0], s = 0.0, wk[TOPK];
                #pragma unroll
                for (int k = 0; k < TOPK; ++k) { wk[k] = exp(tkv[k] - m0); s += wk[k]; }
                double inv = 1.0 / s;
                float myw = 0.f; int myi = 0;
                #pragma unroll
                for (int k = 0; k < TOPK; ++k)
                    if (lane == k) { myw = (float)(wk[k] * inv); myi = tki[k]; }
                if (lane < TOPK) {
                    out_w[(size_t)row * TOPK + lane] = myw;
                    out_i[(size_t)row * TOPK + lane] = (float)myi;
                }
            }
        }
        __syncthreads();   // sRed reuse safe
    }
}

extern "C" void kernel_launch(void* const* d_in, const int* in_sizes, int n_in,
                              void* d_out, int out_size, void* d_ws, size_t ws_size,
                              hipStream_t stream) {
    const float* x     = (const float*)d_in[0];
    const float* noise = (const float*)d_in[1];
    const float* Wg    = (const float*)d_in[2];
    const float* bg    = (const float*)d_in[3];
    const float* Wn    = (const float*)d_in[4];
    float* out = (float*)d_out;
    float* ws  = (float*)d_ws;
    char*  wsW = (char*)d_ws + WSPLIT_BYTE;

    long cap = (long)(ws_size / 4) - WS_LIST;
    int listCap = (int)(cap < 0 ? 0 : (cap > NB ? NB : cap));
    const bool pre = ws_size >= (size_t)WSPLIT_REQ;

    if (pre) {
        hipLaunchKernelGGL(prep_kernel, dim3(129), dim3(256), 0, stream, Wg, Wn, wsW, ws);
        hipLaunchKernelGGL(gate_main_kernel<true>, dim3(NB / BM), dim3(512), 0, stream,
                           x, noise, Wg, bg, Wn, wsW,
                           out, out + (size_t)NB * TOPK, ws, listCap);
    } else {
        hipLaunchKernelGGL(init_ws_kernel, dim3(1), dim3(256), 0, stream, ws);
        hipLaunchKernelGGL(gate_main_kernel<false>, dim3(NB / BM), dim3(512), 0, stream,
                           x, noise, Wg, bg, Wn, wsW,
                           out, out + (size_t)NB * TOPK, ws, listCap);
    }
    hipLaunchKernelGGL(recheck_finalize_kernel, dim3(1024), dim3(512), 0, stream,
                       x, noise, Wg, bg, Wn,
                       out, out + (size_t)NB * TOPK, out + 2 * (size_t)NB * TOPK,
                       ws, listCap);
}